// Round 5
// baseline (91.287 us; speedup 1.0000x reference)
//
#include <hip/hip_runtime.h>

// DBSCAN neighbor-count + classify via augmented-K bf16 MFMA, MI355X (gfx950)
// B=4, N=8192, D=16 fp32 in, int32 out.
// dist(i,j) < EPS=0.5  <=>  x_i.x_j - g_i - g_j > 0,  g_p = 0.5*||x_p||^2 - EPS^2/4
// Augmented point (24 bf16 = 48 B): [x0..x15, 1.0, -g, 0...]
//   A row i swaps k16..17 to [-g_i, 1]; B col j supplies [1, -g_j]
//   => mfma_f32_16x16x32_bf16 with zero C emits x_i.x_j - g_i - g_j directly.
// out[p] = (count_p < 10) ? -1 : 0
//
// R18 = R16 (75.90us, best) + classify FUSED into count via packed
// arrival-counter atomics: each window-block adds cnt + (1<<20) per row;
// the add whose returned old has arrival field == 15 is provably the last
// (all 15 other adds complete & visible in old), so it finalizes the row
// with a plain store of -1/0. Bits 0..19 = count (<= 8192), bits 20+ =
// arrivals (<= 16): no overlap. Deletes the classify kernel launch + its
// 256 KB pass. R17 (32x32 + C-operand thresholds) regressed: per-tile cin
// build cost ~32 VALU-inst per MFMA — falsified. R13-R16 showed count is
// insensitive to staging/atomics/epilogue VALU; remaining lever = launch
// count. Count inner loop below is byte-identical to R16.

constexpr int Np = 8192;
constexpr int Bb = 4;
constexpr int MIN_PTS = 10;
constexpr float EPS2_4 = 0.0625f;  // EPS^2 / 4
constexpr int JS = 16;         // j-windows per batch
constexpr int JW = Np / JS;    // 512 j per window/block
constexpr int ICH = 256;       // i rows per block (4 waves x 64)
constexpr int RF = 4;          // A fragments per wave (16 rows each)
constexpr int NT = JW / 16;    // 32 j-tiles per window

typedef __bf16 bf16x8 __attribute__((ext_vector_type(8)));
typedef float  f32x4  __attribute__((ext_vector_type(4)));

#define GLOBAL_LOAD_LDS16(gptr, lptr)                                          \
    __builtin_amdgcn_global_load_lds(                                          \
        (const __attribute__((address_space(1))) void*)(gptr),                 \
        (__attribute__((address_space(3))) void*)(lptr), 16, 0, 0)

// ---------------- prep: fp32 -> augmented bf16 in window-tiled layout -------
// slot(p, r) = ((b*16 + js)*32 + tl)*48 + r*16 + m, 16 B per slot, where
// js = (p%8192)/512, tl = (p%512)/16, m = p%16.
__global__ __launch_bounds__(256)
void dbscan_prep(const float* __restrict__ x, __bf16* __restrict__ aug,
                 int* __restrict__ out) {
    const int p = blockIdx.x * 256 + threadIdx.x;    // 32768 points
    const float4* src = (const float4*)(x + (size_t)p * 16);
    float4 v0 = src[0], v1 = src[1], v2 = src[2], v3 = src[3];
    float vv[16];
    vv[0]=v0.x; vv[1]=v0.y; vv[2]=v0.z; vv[3]=v0.w;
    vv[4]=v1.x; vv[5]=v1.y; vv[6]=v1.z; vv[7]=v1.w;
    vv[8]=v2.x; vv[9]=v2.y; vv[10]=v2.z; vv[11]=v2.w;
    vv[12]=v3.x; vv[13]=v3.y; vv[14]=v3.z; vv[15]=v3.w;
    float s = 0.f;
#pragma unroll
    for (int k = 0; k < 16; k++) s = fmaf(vv[k], vv[k], s);
    const float g = 0.5f * s - EPS2_4;
    bf16x8 h0, h1, h2;
#pragma unroll
    for (int k = 0; k < 8; k++) { h0[k] = (__bf16)vv[k]; h1[k] = (__bf16)vv[k+8]; }
    h2[0] = (__bf16)1.0f; h2[1] = (__bf16)(-g);
#pragma unroll
    for (int k = 2; k < 8; k++) h2[k] = (__bf16)0.0f;

    const int b   = p >> 13;
    const int pin = p & 8191;
    const int js  = pin >> 9;
    const int tl  = (pin >> 4) & 31;
    const int m   = pin & 15;
    bf16x8* dst = (bf16x8*)aug + (((size_t)(b * 16 + js) * 32 + tl) * 48 + m);
    dst[0]  = h0;   // r = 0
    dst[16] = h1;   // r = 1
    dst[32] = h2;   // r = 2
    out[p] = 0;
}

// ---------------- count: DMA-staged Gram sweep; last arrival classifies ----
// grid: 4 b x 32 i-chunks x 16 j-windows = 2048 blocks, 256 threads.
__global__ __launch_bounds__(256, 6)
void dbscan_count(const __bf16* __restrict__ aug, int* __restrict__ out) {
    const int lane = threadIdx.x & 63;
    const int w    = threadIdx.x >> 6;
    const int m    = lane & 15;          // A/B row-col within tile
    const int q    = lane >> 4;          // k-chunk; C row group
    const int blk  = blockIdx.x;
    const int b    = blk >> 9;
    const int ic   = (blk >> 4) & 31;
    const int js   = blk & 15;
    const int ibase = ic * ICH;

    // LDS image == global window image: [tile][r][m] x 16 B. 24.6 KB.
    __shared__ __bf16 ldsB[NT * 48 * 8];

    // Stage window: pure linear async DMA, 1536 16B-chunks, 6 per thread.
    {
        const __bf16* src = aug + ((size_t)(b * 16 + js) * 32) * 48 * 8;
#pragma unroll
        for (int it = 0; it < 6; it++) {
            const int c = threadIdx.x + it * 256;
            GLOBAL_LOAD_LDS16(src + (size_t)c * 8, ldsB + (size_t)c * 8);
        }
    }

    // A fragments (global, loop-invariant, coalesced: wave reads 1024
    // contiguous B per fragment). Rows: ibase + w*64 + f*16 + m.
    bf16x8 af[RF];
    const int qa = (q < 3) ? q : 2;      // q==3 clamps to a valid addr, zeroed
#pragma unroll
    for (int f = 0; f < RF; f++) {
        const int rowbase = ibase + w * 64 + f * 16;     // uniform, mult of 16
        const int jsA = rowbase >> 9;
        const int tlA = (rowbase >> 4) & 31;
        const __bf16* ap = aug +
            (((size_t)(b * 16 + jsA) * 32 + tlA) * 48 + qa * 16 + m) * 8;
        bf16x8 a = *(const bf16x8*)ap;
        if (q == 2) { __bf16 t = a[0]; a[0] = a[1]; a[1] = t; }  // [1,-g]->[-g,1]
        if (q == 3) {
#pragma unroll
            for (int k = 0; k < 8; k++) a[k] = (__bf16)0.0f;
        }
        af[f] = a;
    }

    __syncthreads();   // drains vmcnt(0): DMA staging complete

    // B fragment address: q<3 -> slot q*16+m; q==3 -> broadcast slot 0 (dead)
    const __bf16* bptr = ldsB + (q < 3 ? (q * 16 + m) * 8 : 0);

    const f32x4 zacc = {0.f, 0.f, 0.f, 0.f};
    int cnt[16];
#pragma unroll
    for (int i = 0; i < 16; i++) cnt[i] = 0;

    bf16x8 bc = *(const bf16x8*)bptr;
#pragma unroll 2
    for (int t = 0; t < NT; t++) {
        const int tn = (t + 1) & (NT - 1);
        bf16x8 bn = *(const bf16x8*)(bptr + tn * 48 * 8);   // depth-1 prefetch
        f32x4 acc[RF];
#pragma unroll
        for (int f = 0; f < RF; f++)
            acc[f] = __builtin_amdgcn_mfma_f32_16x16x32_bf16(af[f], bc, zacc, 0, 0, 0);
        // Rare-positive gate: neighbors (acc>0) are ~diagonal-only for this
        // data. Wave-uniform skip of the accumulate when no lane has one.
        float gm = acc[0][0];
#pragma unroll
        for (int f = 0; f < RF; f++) {
            gm = fmaxf(gm, fmaxf(fmaxf(acc[f][0], acc[f][1]),
                                 fmaxf(acc[f][2], acc[f][3])));
        }
        if (__ballot(gm > 0.0f) != 0ull) {   // scalar branch, rare
#pragma unroll
            for (int f = 0; f < RF; f++) {
                cnt[f*4+0] += (acc[f][0] > 0.0f) ? 1 : 0;
                cnt[f*4+1] += (acc[f][1] > 0.0f) ? 1 : 0;
                cnt[f*4+2] += (acc[f][2] > 0.0f) ? 1 : 0;
                cnt[f*4+3] += (acc[f][3] > 0.0f) ? 1 : 0;
            }
        }
        bc = bn;
    }

    // Sum across the 16 cols (lane bits 0..3); lane m==0 of each q adds rows.
#pragma unroll
    for (int i = 0; i < 16; i++) {
        int v = cnt[i];
        v += __shfl_xor(v, 1);
        v += __shfl_xor(v, 2);
        v += __shfl_xor(v, 4);
        v += __shfl_xor(v, 8);
        cnt[i] = v;
    }
    if (m == 0) {
        int* ob = out + (size_t)b * Np + ibase + w * 64;
        // Packed arrival-counter atomic: bits 0..19 = count (<= 8192),
        // bits 20+ = arrivals (16 max). The 16th arriver (old>>20 == 15)
        // has proof all other adds completed -> finalize row with -1/0.
#pragma unroll
        for (int f = 0; f < RF; f++)
#pragma unroll
            for (int r = 0; r < 4; r++) {
                const int row = f * 16 + q * 4 + r;
                const int old = atomicAdd(&ob[row], cnt[f*4+r] + (1 << 20));
                if ((old >> 20) == 15) {
                    const int total = (old & 0xFFFFF) + cnt[f*4+r];
                    ob[row] = (total < MIN_PTS) ? -1 : 0;
                }
            }
    }
}

extern "C" void kernel_launch(void* const* d_in, const int* in_sizes, int n_in,
                              void* d_out, int out_size, void* d_ws, size_t ws_size,
                              hipStream_t stream) {
    const float* x = (const float*)d_in[0];
    int* out = (int*)d_out;
    __bf16* aug = (__bf16*)d_ws;   // 4*16*32*48*16 B = 1.5 MB, window-tiled

    dbscan_prep<<<dim3(Bb * Np / 256), dim3(256), 0, stream>>>(x, aug, out);
    dbscan_count<<<dim3(Bb * 32 * JS), dim3(256), 0, stream>>>(aug, out);
}

// Round 6
// 80.377 us; speedup vs baseline: 1.1357x; 1.1357x over previous
//
#include <hip/hip_runtime.h>

// DBSCAN neighbor-count + classify via augmented-K bf16 MFMA, MI355X (gfx950)
// B=4, N=8192, D=16 fp32 in, int32 out.
// dist(i,j) < EPS=0.5  <=>  x_i.x_j - g_i - g_j > 0,  g_p = 0.5*||x_p||^2 - EPS^2/4
// Augmented point (24 bf16 = 48 B): [x0..x15, 1.0, -g, 0...]
//   A row i swaps k16..17 to [-g_i, 1]; B col j supplies [1, -g_j]
//   => mfma_f32_16x16x32_bf16 with zero C emits x_i.x_j - g_i - g_j directly.
// out[p] = (count_p < 10) ? -1 : 0
//
// R19 = R16 revert (75.90us best; R18's RETURNING atomics cost +18us on
// count — falsified, back to fire-and-forget + classify kernel) + ONE new
// lever from R18's first-ever count counters (MfmaUtil 14.6, VALUBusy 28.6,
// Occupancy 31.6%): count is LATENCY-bound, pipes idle, occupancy capped by
// LDS (24.6KB -> 6 blocks/CU). Halve the j-window: JS 16->32, JW 256, LDS
// 12.3KB -> 8 blocks x 4 waves = 32 waves/CU (wave-slot cap), grid 4096.
// Total staged bytes unchanged; A-frag re-reads 2x (L2-resident, trivial);
// atomics 2x (non-returning, proven free R13-R16). Inner loop unchanged.

constexpr int Np = 8192;
constexpr int Bb = 4;
constexpr int MIN_PTS = 10;
constexpr float EPS2_4 = 0.0625f;  // EPS^2 / 4
constexpr int JS = 32;         // j-windows per batch
constexpr int JW = Np / JS;    // 256 j per window/block
constexpr int ICH = 256;       // i rows per block (4 waves x 64)
constexpr int RF = 4;          // A fragments per wave (16 rows each)
constexpr int NT = JW / 16;    // 16 j-tiles per window
constexpr int NTILE = Np / 16; // 512 16-point tiles per batch (layout)

typedef __bf16 bf16x8 __attribute__((ext_vector_type(8)));
typedef float  f32x4  __attribute__((ext_vector_type(4)));

#define GLOBAL_LOAD_LDS16(gptr, lptr)                                          \
    __builtin_amdgcn_global_load_lds(                                          \
        (const __attribute__((address_space(1))) void*)(gptr),                 \
        (__attribute__((address_space(3))) void*)(lptr), 16, 0, 0)

// ---------------- prep: fp32 -> augmented bf16 in window-tiled layout -------
// slot(p, r) = ((b*JS + js)*(JW/16) + tl)*48 + r*16 + m, 16 B per slot, where
// js = (p%8192)/JW, tl = (p%JW)/16, m = p%16.
__global__ __launch_bounds__(256)
void dbscan_prep(const float* __restrict__ x, __bf16* __restrict__ aug,
                 int* __restrict__ out) {
    const int p = blockIdx.x * 256 + threadIdx.x;    // 32768 points
    const float4* src = (const float4*)(x + (size_t)p * 16);
    float4 v0 = src[0], v1 = src[1], v2 = src[2], v3 = src[3];
    float vv[16];
    vv[0]=v0.x; vv[1]=v0.y; vv[2]=v0.z; vv[3]=v0.w;
    vv[4]=v1.x; vv[5]=v1.y; vv[6]=v1.z; vv[7]=v1.w;
    vv[8]=v2.x; vv[9]=v2.y; vv[10]=v2.z; vv[11]=v2.w;
    vv[12]=v3.x; vv[13]=v3.y; vv[14]=v3.z; vv[15]=v3.w;
    float s = 0.f;
#pragma unroll
    for (int k = 0; k < 16; k++) s = fmaf(vv[k], vv[k], s);
    const float g = 0.5f * s - EPS2_4;
    bf16x8 h0, h1, h2;
#pragma unroll
    for (int k = 0; k < 8; k++) { h0[k] = (__bf16)vv[k]; h1[k] = (__bf16)vv[k+8]; }
    h2[0] = (__bf16)1.0f; h2[1] = (__bf16)(-g);
#pragma unroll
    for (int k = 2; k < 8; k++) h2[k] = (__bf16)0.0f;

    const int b   = p >> 13;
    const int pin = p & 8191;
    const int tile = pin >> 4;          // global tile index within batch
    const int m   = pin & 15;
    bf16x8* dst = (bf16x8*)aug + (((size_t)b * NTILE + tile) * 48 + m);
    dst[0]  = h0;   // r = 0
    dst[16] = h1;   // r = 1
    dst[32] = h2;   // r = 2
    out[p] = 0;
}

// ---------------- count: DMA-staged Gram sweep, atomicAdd partials ----------
// grid: 4 b x 32 i-chunks x 32 j-windows = 4096 blocks, 256 threads.
__global__ __launch_bounds__(256, 8)
void dbscan_count(const __bf16* __restrict__ aug, int* __restrict__ out) {
    const int lane = threadIdx.x & 63;
    const int w    = threadIdx.x >> 6;
    const int m    = lane & 15;          // A/B row-col within tile
    const int q    = lane >> 4;          // k-chunk; C row group
    const int blk  = blockIdx.x;
    const int b    = blk >> 10;
    const int ic   = (blk >> 5) & 31;
    const int js   = blk & 31;
    const int ibase = ic * ICH;

    // LDS image == global window image: [tile][r][m] x 16 B. 12.3 KB.
    __shared__ __bf16 ldsB[NT * 48 * 8];

    // Stage window: pure linear async DMA, 768 16B-chunks, 3 per thread.
    {
        const __bf16* src = aug + ((size_t)b * NTILE + (size_t)js * NT) * 48 * 8;
#pragma unroll
        for (int it = 0; it < 3; it++) {
            const int c = threadIdx.x + it * 256;
            GLOBAL_LOAD_LDS16(src + (size_t)c * 8, ldsB + (size_t)c * 8);
        }
    }

    // A fragments (global, loop-invariant, coalesced: wave reads 1024
    // contiguous B per fragment). Rows: ibase + w*64 + f*16 + m.
    bf16x8 af[RF];
    const int qa = (q < 3) ? q : 2;      // q==3 clamps to a valid addr, zeroed
#pragma unroll
    for (int f = 0; f < RF; f++) {
        const int tileA = (ibase + w * 64 + f * 16) >> 4;    // uniform
        const __bf16* ap = aug +
            (((size_t)b * NTILE + tileA) * 48 + qa * 16 + m) * 8;
        bf16x8 a = *(const bf16x8*)ap;
        if (q == 2) { __bf16 t = a[0]; a[0] = a[1]; a[1] = t; }  // [1,-g]->[-g,1]
        if (q == 3) {
#pragma unroll
            for (int k = 0; k < 8; k++) a[k] = (__bf16)0.0f;
        }
        af[f] = a;
    }

    __syncthreads();   // drains vmcnt(0): DMA staging complete

    // B fragment address: q<3 -> slot q*16+m; q==3 -> broadcast slot 0 (dead)
    const __bf16* bptr = ldsB + (q < 3 ? (q * 16 + m) * 8 : 0);

    const f32x4 zacc = {0.f, 0.f, 0.f, 0.f};
    int cnt[16];
#pragma unroll
    for (int i = 0; i < 16; i++) cnt[i] = 0;

    bf16x8 bc = *(const bf16x8*)bptr;
#pragma unroll 2
    for (int t = 0; t < NT; t++) {
        const int tn = (t + 1) & (NT - 1);
        bf16x8 bn = *(const bf16x8*)(bptr + tn * 48 * 8);   // depth-1 prefetch
        f32x4 acc[RF];
#pragma unroll
        for (int f = 0; f < RF; f++)
            acc[f] = __builtin_amdgcn_mfma_f32_16x16x32_bf16(af[f], bc, zacc, 0, 0, 0);
        // Rare-positive gate: neighbors (acc>0) are ~diagonal-only for this
        // data. Wave-uniform skip of the accumulate when no lane has one.
        float gm = acc[0][0];
#pragma unroll
        for (int f = 0; f < RF; f++) {
            gm = fmaxf(gm, fmaxf(fmaxf(acc[f][0], acc[f][1]),
                                 fmaxf(acc[f][2], acc[f][3])));
        }
        if (__ballot(gm > 0.0f) != 0ull) {   // scalar branch, rare
#pragma unroll
            for (int f = 0; f < RF; f++) {
                cnt[f*4+0] += (acc[f][0] > 0.0f) ? 1 : 0;
                cnt[f*4+1] += (acc[f][1] > 0.0f) ? 1 : 0;
                cnt[f*4+2] += (acc[f][2] > 0.0f) ? 1 : 0;
                cnt[f*4+3] += (acc[f][3] > 0.0f) ? 1 : 0;
            }
        }
        bc = bn;
    }

    // Sum across the 16 cols (lane bits 0..3); lane m==0 of each q adds rows.
#pragma unroll
    for (int i = 0; i < 16; i++) {
        int v = cnt[i];
        v += __shfl_xor(v, 1);
        v += __shfl_xor(v, 2);
        v += __shfl_xor(v, 4);
        v += __shfl_xor(v, 8);
        cnt[i] = v;
    }
    if (m == 0) {
        int* ob = out + (size_t)b * Np + ibase + w * 64;
#pragma unroll
        for (int f = 0; f < RF; f++)
#pragma unroll
            for (int r = 0; r < 4; r++)
                atomicAdd(&ob[f*16 + q*4 + r], cnt[f*4+r]);
    }
}

// ---------------- classify ----------------
__global__ __launch_bounds__(256)
void dbscan_classify(int* __restrict__ out) {
    const int p = blockIdx.x * 256 + threadIdx.x;
    out[p] = (out[p] < MIN_PTS) ? -1 : 0;
}

extern "C" void kernel_launch(void* const* d_in, const int* in_sizes, int n_in,
                              void* d_out, int out_size, void* d_ws, size_t ws_size,
                              hipStream_t stream) {
    const float* x = (const float*)d_in[0];
    int* out = (int*)d_out;
    __bf16* aug = (__bf16*)d_ws;   // 32768 * 48 B = 1.5 MB, window-tiled

    dbscan_prep<<<dim3(Bb * Np / 256), dim3(256), 0, stream>>>(x, aug, out);
    dbscan_count<<<dim3(Bb * 32 * JS), dim3(256), 0, stream>>>(aug, out);
    dbscan_classify<<<dim3(Bb * Np / 256), dim3(256), 0, stream>>>(out);
}

// Round 8
// 75.832 us; speedup vs baseline: 1.2038x; 1.0599x over previous
//
#include <hip/hip_runtime.h>

// DBSCAN neighbor-count + classify via augmented-K bf16 MFMA, MI355X (gfx950)
// B=4, N=8192, D=16 fp32 in, int32 out.
// dist(i,j) < EPS=0.5  <=>  x_i.x_j - g_i - g_j > 0,  g_p = 0.5*||x_p||^2 - EPS^2/4
// Augmented point (24 bf16 = 48 B): [x0..x15, 1.0, -g, 0...]
//   A row i swaps k16..17 to [-g_i, 1]; B col j supplies [1, -g_j]
//   => mfma_f32_16x16x32_bf16 with zero C emits x_i.x_j - g_i - g_j directly.
// out[p] = (count_p < 10) ? -1 : 0
//
// R21 = exact revert to R16 (75.90us, session best, passing) + int4
// classify (zero-risk). R20 (8-wave/512-thread) FAILED the replay
// tripwire for unexplained reasons -> reverted on principle. Session
// ledger vs R16: R14 staging-DMA neutral; R15 atomic-free -4.4; R17
// 32x32 -5.2; R18 returning-atomic fusion -15.4; R19 small-window
// occupancy -4.5; R20 fail. Wall-clock = ~41us harness poison fill
// (268MB, same-stream, fixed) + ~33us kernel chain at its measured
// plateau. If this round reproduces ~76us, the next action is ROOFLINE.

constexpr int Np = 8192;
constexpr int Bb = 4;
constexpr int MIN_PTS = 10;
constexpr float EPS2_4 = 0.0625f;  // EPS^2 / 4
constexpr int JS = 16;         // j-windows per batch
constexpr int JW = Np / JS;    // 512 j per window/block
constexpr int ICH = 256;       // i rows per block (4 waves x 64)
constexpr int RF = 4;          // A fragments per wave (16 rows each)
constexpr int NT = JW / 16;    // 32 j-tiles per window

typedef __bf16 bf16x8 __attribute__((ext_vector_type(8)));
typedef float  f32x4  __attribute__((ext_vector_type(4)));

#define GLOBAL_LOAD_LDS16(gptr, lptr)                                          \
    __builtin_amdgcn_global_load_lds(                                          \
        (const __attribute__((address_space(1))) void*)(gptr),                 \
        (__attribute__((address_space(3))) void*)(lptr), 16, 0, 0)

// ---------------- prep: fp32 -> augmented bf16 in window-tiled layout -------
// slot(p, r) = ((b*16 + js)*32 + tl)*48 + r*16 + m, 16 B per slot, where
// js = (p%8192)/512, tl = (p%512)/16, m = p%16.
__global__ __launch_bounds__(256)
void dbscan_prep(const float* __restrict__ x, __bf16* __restrict__ aug,
                 int* __restrict__ out) {
    const int p = blockIdx.x * 256 + threadIdx.x;    // 32768 points
    const float4* src = (const float4*)(x + (size_t)p * 16);
    float4 v0 = src[0], v1 = src[1], v2 = src[2], v3 = src[3];
    float vv[16];
    vv[0]=v0.x; vv[1]=v0.y; vv[2]=v0.z; vv[3]=v0.w;
    vv[4]=v1.x; vv[5]=v1.y; vv[6]=v1.z; vv[7]=v1.w;
    vv[8]=v2.x; vv[9]=v2.y; vv[10]=v2.z; vv[11]=v2.w;
    vv[12]=v3.x; vv[13]=v3.y; vv[14]=v3.z; vv[15]=v3.w;
    float s = 0.f;
#pragma unroll
    for (int k = 0; k < 16; k++) s = fmaf(vv[k], vv[k], s);
    const float g = 0.5f * s - EPS2_4;
    bf16x8 h0, h1, h2;
#pragma unroll
    for (int k = 0; k < 8; k++) { h0[k] = (__bf16)vv[k]; h1[k] = (__bf16)vv[k+8]; }
    h2[0] = (__bf16)1.0f; h2[1] = (__bf16)(-g);
#pragma unroll
    for (int k = 2; k < 8; k++) h2[k] = (__bf16)0.0f;

    const int b   = p >> 13;
    const int pin = p & 8191;
    const int js  = pin >> 9;
    const int tl  = (pin >> 4) & 31;
    const int m   = pin & 15;
    bf16x8* dst = (bf16x8*)aug + (((size_t)(b * 16 + js) * 32 + tl) * 48 + m);
    dst[0]  = h0;   // r = 0
    dst[16] = h1;   // r = 1
    dst[32] = h2;   // r = 2
    out[p] = 0;
}

// ---------------- count: DMA-staged Gram sweep, atomicAdd partials ----------
// grid: 4 b x 32 i-chunks x 16 j-windows = 2048 blocks, 256 threads.
__global__ __launch_bounds__(256, 6)
void dbscan_count(const __bf16* __restrict__ aug, int* __restrict__ out) {
    const int lane = threadIdx.x & 63;
    const int w    = threadIdx.x >> 6;
    const int m    = lane & 15;          // A/B row-col within tile
    const int q    = lane >> 4;          // k-chunk; C row group
    const int blk  = blockIdx.x;
    const int b    = blk >> 9;
    const int ic   = (blk >> 4) & 31;
    const int js   = blk & 15;
    const int ibase = ic * ICH;

    // LDS image == global window image: [tile][r][m] x 16 B. 24.6 KB.
    __shared__ __bf16 ldsB[NT * 48 * 8];

    // Stage window: pure linear async DMA, 1536 16B-chunks, 6 per thread.
    {
        const __bf16* src = aug + ((size_t)(b * 16 + js) * 32) * 48 * 8;
#pragma unroll
        for (int it = 0; it < 6; it++) {
            const int c = threadIdx.x + it * 256;
            GLOBAL_LOAD_LDS16(src + (size_t)c * 8, ldsB + (size_t)c * 8);
        }
    }

    // A fragments (global, loop-invariant, coalesced: wave reads 1024
    // contiguous B per fragment). Rows: ibase + w*64 + f*16 + m.
    bf16x8 af[RF];
    const int qa = (q < 3) ? q : 2;      // q==3 clamps to a valid addr, zeroed
#pragma unroll
    for (int f = 0; f < RF; f++) {
        const int rowbase = ibase + w * 64 + f * 16;     // uniform, mult of 16
        const int jsA = rowbase >> 9;
        const int tlA = (rowbase >> 4) & 31;
        const __bf16* ap = aug +
            (((size_t)(b * 16 + jsA) * 32 + tlA) * 48 + qa * 16 + m) * 8;
        bf16x8 a = *(const bf16x8*)ap;
        if (q == 2) { __bf16 t = a[0]; a[0] = a[1]; a[1] = t; }  // [1,-g]->[-g,1]
        if (q == 3) {
#pragma unroll
            for (int k = 0; k < 8; k++) a[k] = (__bf16)0.0f;
        }
        af[f] = a;
    }

    __syncthreads();   // drains vmcnt(0): DMA staging complete

    // B fragment address: q<3 -> slot q*16+m; q==3 -> broadcast slot 0 (dead)
    const __bf16* bptr = ldsB + (q < 3 ? (q * 16 + m) * 8 : 0);

    const f32x4 zacc = {0.f, 0.f, 0.f, 0.f};
    int cnt[16];
#pragma unroll
    for (int i = 0; i < 16; i++) cnt[i] = 0;

    bf16x8 bc = *(const bf16x8*)bptr;
#pragma unroll 2
    for (int t = 0; t < NT; t++) {
        const int tn = (t + 1) & (NT - 1);
        bf16x8 bn = *(const bf16x8*)(bptr + tn * 48 * 8);   // depth-1 prefetch
        f32x4 acc[RF];
#pragma unroll
        for (int f = 0; f < RF; f++)
            acc[f] = __builtin_amdgcn_mfma_f32_16x16x32_bf16(af[f], bc, zacc, 0, 0, 0);
        // Rare-positive gate: neighbors (acc>0) are ~diagonal-only for this
        // data. Wave-uniform skip of the accumulate when no lane has one.
        float gm = acc[0][0];
#pragma unroll
        for (int f = 0; f < RF; f++) {
            gm = fmaxf(gm, fmaxf(fmaxf(acc[f][0], acc[f][1]),
                                 fmaxf(acc[f][2], acc[f][3])));
        }
        if (__ballot(gm > 0.0f) != 0ull) {   // scalar branch, rare
#pragma unroll
            for (int f = 0; f < RF; f++) {
                cnt[f*4+0] += (acc[f][0] > 0.0f) ? 1 : 0;
                cnt[f*4+1] += (acc[f][1] > 0.0f) ? 1 : 0;
                cnt[f*4+2] += (acc[f][2] > 0.0f) ? 1 : 0;
                cnt[f*4+3] += (acc[f][3] > 0.0f) ? 1 : 0;
            }
        }
        bc = bn;
    }

    // Sum across the 16 cols (lane bits 0..3); lane m==0 of each q adds rows.
#pragma unroll
    for (int i = 0; i < 16; i++) {
        int v = cnt[i];
        v += __shfl_xor(v, 1);
        v += __shfl_xor(v, 2);
        v += __shfl_xor(v, 4);
        v += __shfl_xor(v, 8);
        cnt[i] = v;
    }
    if (m == 0) {
        int* ob = out + (size_t)b * Np + ibase + w * 64;
#pragma unroll
        for (int f = 0; f < RF; f++)
#pragma unroll
            for (int r = 0; r < 4; r++)
                atomicAdd(&ob[f*16 + q*4 + r], cnt[f*4+r]);
    }
}

// ---------------- classify: int4-vectorized RMW ----------------
__global__ __launch_bounds__(256)
void dbscan_classify(int* __restrict__ out) {
    const int i = blockIdx.x * 256 + threadIdx.x;    // 8192 threads x int4
    int4* o4 = (int4*)out;
    int4 v = o4[i];
    v.x = (v.x < MIN_PTS) ? -1 : 0;
    v.y = (v.y < MIN_PTS) ? -1 : 0;
    v.z = (v.z < MIN_PTS) ? -1 : 0;
    v.w = (v.w < MIN_PTS) ? -1 : 0;
    o4[i] = v;
}

extern "C" void kernel_launch(void* const* d_in, const int* in_sizes, int n_in,
                              void* d_out, int out_size, void* d_ws, size_t ws_size,
                              hipStream_t stream) {
    const float* x = (const float*)d_in[0];
    int* out = (int*)d_out;
    __bf16* aug = (__bf16*)d_ws;   // 4*16*32*48*16 B = 1.5 MB, window-tiled

    dbscan_prep<<<dim3(Bb * Np / 256), dim3(256), 0, stream>>>(x, aug, out);
    dbscan_count<<<dim3(Bb * 32 * JS), dim3(256), 0, stream>>>(aug, out);
    dbscan_classify<<<dim3(Bb * Np / 1024), dim3(256), 0, stream>>>(out);
}